// Round 6
// baseline (43.434 us; speedup 1.0000x reference)
//
#include <hip/hip_runtime.h>

#define B_N 2048
#define E_N 64
#define D_N 512
#define O_N 512
#define MC  32   // sample rows per chunk
#define NT  16   // 32-k tiles

typedef __bf16 bf16x8 __attribute__((ext_vector_type(8)));
typedef float  f32x4  __attribute__((ext_vector_type(4)));

__device__ __forceinline__ unsigned short f2bf(float f) {
  unsigned int u = __float_as_uint(f);
  u = (u + 0x7FFFu + ((u >> 16) & 1u)) >> 16;  // RNE
  return (unsigned short)u;
}

// 8 blocks x 256: global-atomic bucketing (output is order-invariant).
__global__ __launch_bounds__(256)
void bucket_kernel(const int* __restrict__ opt, int* __restrict__ cnt,
                   int* __restrict__ list) {
  int b = blockIdx.x * 256 + threadIdx.x;
  int e = opt[b];
  int slot = atomicAdd(&cnt[e], 1);
  list[e * B_N + slot] = b;
}

// Grouped GEMM: block = (expert, 64-col slab), 512 threads = 8 waves =
// 2 row-groups (16 rows) x 4 col-groups (16 cols); 32-row m-chunks.
// W streamed via global_load_lds into a 4-deep ring of 8 KB fp32 tiles
// (DMA issued 3 barrier-phases ahead of use -> latency hidden), counted
// vmcnt(3) waits, never 0 in the loop. All LDS mappings identical to the
// round-3 hardware-verified kernel.
__global__ __launch_bounds__(512)
void gemm_kernel(const float* __restrict__ x, const float* __restrict__ w,
                 const float* __restrict__ bias, const int* __restrict__ cnt,
                 const int* __restrict__ list, float* __restrict__ out) {
  __shared__ unsigned short xs[MC * 512];  // 32 KB bf16, XOR-swizzled rows
  __shared__ float ws[4][32 * 64];         // 4 x 8 KB fp32 W-tile ring

  const int e    = blockIdx.x;
  const int o0   = blockIdx.y * 64;
  const int t    = threadIdx.x;
  const int lane = t & 63;
  const int wave = t >> 6;
  const int wc   = wave & 3;    // col-group (16 cols)
  const int wg   = wave >> 2;   // row-group (16 rows)
  const int n    = cnt[e];
  if (n == 0) return;

  const float* wexp = w + (size_t)e * D_N * O_N;
  const int m_in  = lane & 15;
  const int g     = lane >> 4;
  const int col64 = wc * 16 + m_in;
  const float bval = bias[e * O_N + o0 + col64];
  const int* mylist = list + e * B_N;
  const int r0   = wg * 16 + m_in;       // A-row in xs (0..31)
  const int akey = (r0 & 7) << 3;
  const int csw  = col64 ^ (g << 4);     // B read-side swizzle (R3-verified)

  // DMA source geometry (R3-verified): wave covers tile k-rows 4w..4w+3,
  // lane i -> dest bytes [i*16, i*16+16) of ws[slot][wave*256 ...].
  const int dk   = 4 * wave + (lane >> 4);
  const int skey = ((dk >> 3) & 3) << 4;
  const int scol = ((lane & 15) * 4) ^ skey;

#define DMA_T(TT) do {                                                         \
    const float* _src =                                                        \
        wexp + (size_t)(((TT) & 15) * 32 + dk) * O_N + o0 + scol;              \
    __builtin_amdgcn_global_load_lds(                                          \
        (const __attribute__((address_space(1))) void*)_src,                   \
        (__attribute__((address_space(3))) void*)&ws[(TT) & 3][wave * 256],    \
        16, 0, 0);                                                             \
  } while (0)

#define COMPUTE(KT) do {                                                       \
    const float* wsp = &ws[(KT) & 3][0];                                       \
    const int kk = ((KT) * 32 + g * 8) ^ akey;                                 \
    union { uint4 u; bf16x8 v; } a0;                                           \
    a0.u = *reinterpret_cast<const uint4*>(&xs[r0 * 512 + kk]);                \
    union { unsigned short us[8]; bf16x8 v; } bw;                              \
    _Pragma("unroll")                                                          \
    for (int j = 0; j < 8; ++j) bw.us[j] = f2bf(wsp[(g * 8 + j) * 64 + csw]);  \
    acc0 = __builtin_amdgcn_mfma_f32_16x16x32_bf16(a0.v, bw.v, acc0, 0, 0, 0); \
  } while (0)

  for (int m0 = 0; m0 < n; m0 += MC) {
    __syncthreads();             // xs/ws safe to overwrite (drains all vmem)
    // Stage MC x 512 fp32 -> bf16 LDS (XOR-swizzled): 4096 float4 / 512 thr.
#pragma unroll
    for (int i = 0; i < 8; ++i) {
      int idx = t + i * 512;
      int row = idx >> 7;
      int c4  = idx & 127;
      int s   = m0 + row;
      ushort4 v = make_ushort4(0, 0, 0, 0);
      if (s < n) {
        const float4 xv = *reinterpret_cast<const float4*>(x + (size_t)mylist[s] * D_N + c4 * 4);
        v = make_ushort4(f2bf(xv.x), f2bf(xv.y), f2bf(xv.z), f2bf(xv.w));
      }
      *reinterpret_cast<ushort4*>(&xs[row * 512 + ((c4 * 4) ^ ((row & 7) << 3))]) = v;
    }
    __syncthreads();             // staging loads fully drained (vmcnt 0)

    f32x4 acc0 = {0.f, 0.f, 0.f, 0.f};

    DMA_T(0); DMA_T(1); DMA_T(2);          // ring prologue: 3 in flight
#pragma unroll 1
    for (int kt = 0; kt < NT; ++kt) {
      DMA_T(kt + 3);                       // 4 in flight (wraps harmlessly at tail)
      asm volatile("s_waitcnt vmcnt(3)\ns_barrier" ::: "memory");  // tile kt landed
      COMPUTE(kt);
      asm volatile("s_waitcnt lgkmcnt(0)\ns_barrier" ::: "memory"); // reads retired
    }

    // D layout (m89-verified): col = lane&15, row = (lane>>4)*4 + reg
#pragma unroll
    for (int r = 0; r < 4; ++r) {
      int sl = wg * 16 + g * 4 + r;
      int s  = m0 + sl;
      if (s < n) out[(size_t)mylist[s] * O_N + o0 + col64] = acc0[r] + bval;
    }
  }
  asm volatile("s_waitcnt vmcnt(0)" ::: "memory");  // drain tail dummy DMAs
#undef DMA_T
#undef COMPUTE
}

extern "C" void kernel_launch(void* const* d_in, const int* in_sizes, int n_in,
                              void* d_out, int out_size, void* d_ws, size_t ws_size,
                              hipStream_t stream) {
  const float* x      = (const float*)d_in[0];
  const int*   option = (const int*)d_in[1];
  const float* weight = (const float*)d_in[2];
  const float* bias   = (const float*)d_in[3];
  float* out = (float*)d_out;

  int* cnt  = (int*)d_ws;                    // 64 ints
  int* list = (int*)((char*)d_ws + 256);     // 64 * 2048 ints

  hipMemsetAsync(cnt, 0, E_N * sizeof(int), stream);
  bucket_kernel<<<B_N / 256, 256, 0, stream>>>(option, cnt, list);
  gemm_kernel<<<dim3(E_N, O_N / 64), 512, 0, stream>>>(x, weight, bias, cnt, list, out);
}